// Round 9
// baseline (502.316 us; speedup 1.0000x reference)
//
#include <hip/hip_runtime.h>
#include <stdint.h>

#define N_POINTS   1048576
#define N_LEVELS   16
#define HASHMAP    524288u        // 1<<19
#define HASH_MASK  (HASHMAP - 1u)
#define PI1        2654435761u
#define PI2        805459861u
#define NBUCKET    8192           // 13-bit Morton key: x res-32, y/z res-16
#define HBLK       256            // hist/scatter blocks
#define PPB        4096           // points per hist/scatter block
#define PADIDX(j)  ((j) + ((j) >> 5))   // LDS pad: +1 per 32 -> conflict-free serial scan

typedef float v2  __attribute__((ext_vector_type(2)));   // one table entry (8B)
typedef float v4f __attribute__((ext_vector_type(4)));   // 16B chunk

// int(16 * (32^(1/15))^i) for i in 0..15, replicated exactly from the reference
__constant__ float c_res[16] = {16.f,20.f,25.f,32.f,40.f,50.f,64.f,80.f,
                                101.f,128.f,161.f,203.f,256.f,322.f,406.f,512.f};
// phase order: alternate coarse/fine so adjacent-in-time levels' tables fit L2
__constant__ int c_perm[16] = {0,15,1,14,2,13,3,12,4,11,5,10,6,9,7,8};

// ---- gather core (round-0 verified; request-bound with sorted input)
__device__ __forceinline__ v2 enc_point_level(float x0, float x1, float x2,
                                              const float* __restrict__ tables,
                                              int level, float res) {
    float sx = x0*res, sy = x1*res, sz = x2*res;
    int ix = (int)sx, iy = (int)sy, iz = (int)sz;   // trunc == floor for x>=0
    float fx = sx - (float)ix, fy = sy - (float)iy, fz = sz - (float)iz;
    uint32_t hx0 = (uint32_t)ix,       hx1 = hx0 + 1u;
    uint32_t hy0 = (uint32_t)iy * PI1, hy1 = hy0 + PI1;
    uint32_t hz0 = (uint32_t)iz * PI2, hz1 = hz0 + PI2;
    const v2* __restrict__ tab = (const v2*)tables + (size_t)level * HASHMAP;
    uint32_t e0 = hy0 ^ hz0, e1 = hy1 ^ hz0, e2 = hy0 ^ hz1, e3 = hy1 ^ hz1;
    v2 f0 = tab[(hx0 ^ e0) & HASH_MASK], f1 = tab[(hx1 ^ e0) & HASH_MASK];
    v2 f2 = tab[(hx0 ^ e1) & HASH_MASK], f3 = tab[(hx1 ^ e1) & HASH_MASK];
    v2 f4 = tab[(hx0 ^ e2) & HASH_MASK], f5 = tab[(hx1 ^ e2) & HASH_MASK];
    v2 f6 = tab[(hx0 ^ e3) & HASH_MASK], f7 = tab[(hx1 ^ e3) & HASH_MASK];
    float wx1 = fx, wx0 = 1.f - fx;
    float wy1 = fy, wy0 = 1.f - fy;
    float wz1 = fz, wz0 = 1.f - fz;
    float w00 = wy0*wz0, w10 = wy1*wz0, w01 = wy0*wz1, w11 = wy1*wz1;
    float c0 = wx0*w00, c1 = wx1*w00, c2 = wx0*w10, c3 = wx1*w10;
    float c4 = wx0*w01, c5 = wx1*w01, c6 = wx0*w11, c7 = wx1*w11;
    v2 r;
    r.x = c0*f0.x + c1*f1.x + c2*f2.x + c3*f3.x + c4*f4.x + c5*f5.x + c6*f6.x + c7*f7.x;
    r.y = c0*f0.y + c1*f1.y + c2*f2.y + c3*f3.y + c4*f4.y + c5*f5.y + c6*f6.y + c7*f7.y;
    return r;
}

__device__ __forceinline__ uint32_t part1by2(uint32_t v) {
    v = (v | (v << 16)) & 0x030000FFu;
    v = (v | (v <<  8)) & 0x0300F00Fu;
    v = (v | (v <<  4)) & 0x030C30C3u;
    v = (v | (v <<  2)) & 0x09249249u;
    return v;
}
// 13-bit key: standard 12-bit Morton of (ix>>1, iy, iz) with the finest x bit
// as LSB. x at res-32 (recovers mid-level dedup), y/z at res-16.
__device__ __forceinline__ uint32_t morton13(float x0, float x1, float x2) {
    uint32_t ix = (uint32_t)(int)(x0 * 32.f);   // 0..31
    uint32_t iy = (uint32_t)(int)(x1 * 16.f);   // 0..15
    uint32_t iz = (uint32_t)(int)(x2 * 16.f);   // 0..15
    uint32_t m = part1by2(ix >> 1) | (part1by2(iy) << 1) | (part1by2(iz) << 2);
    return (m << 1) | (ix & 1u);
}

// ---- 0a: per-block LDS histogram -> coalesced row write. Zero global atomics.
__global__ __launch_bounds__(256) void k_hist(const float* __restrict__ x,
                                              uint32_t* __restrict__ M) {
    __shared__ uint32_t h[NBUCKET];              // 32 KB
    int t = threadIdx.x, blk = blockIdx.x;
    for (int j = t; j < NBUCKET; j += 256) h[j] = 0;
    __syncthreads();
    int base = blk * PPB;
    for (int it = 0; it < PPB / 256; ++it) {
        int p = base + it * 256 + t;
        uint32_t k = morton13(x[3*p], x[3*p+1], x[3*p+2]);
        atomicAdd(&h[k], 1u);                    // LDS atomic
    }
    __syncthreads();
    for (int j = t; j < NBUCKET; j += 256)
        M[(size_t)blk * NBUCKET + j] = h[j];
}

// ---- 0b: per-bucket exclusive scan across the 256 hist-blocks (+ totals T).
__global__ __launch_bounds__(256) void k_scanA(uint32_t* __restrict__ M,
                                               uint32_t* __restrict__ T) {
    __shared__ uint32_t s[256];
    int t = threadIdx.x, b = blockIdx.x;
    uint32_t v0 = M[(size_t)t * NBUCKET + b];
    s[t] = v0;
    __syncthreads();
    #pragma unroll
    for (int off = 1; off < 256; off <<= 1) {
        uint32_t v = (t >= off) ? s[t - off] : 0;
        __syncthreads();
        s[t] += v;
        __syncthreads();
    }
    M[(size_t)t * NBUCKET + b] = s[t] - v0;      // excl. prefix over hist-blocks
    if (t == 255) T[b] = s[t];                   // bucket total
}

// ---- 0c: scatter. ONE padded LDS array: cur[k] starts at
// Tpref[k] + M[blk][k] (this block's segment start in bucket k), and
// atomicAdd(&cur[k],1) then yields the global position directly.
// Tpref computed by a redundant in-block scan of T (no extra dispatch).
// Zero global atomics; one coalesced read + one 16B scattered store per point.
__global__ __launch_bounds__(256) void k_scatter(const float* __restrict__ x,
                                                 const uint32_t* __restrict__ M,
                                                 const uint32_t* __restrict__ T,
                                                 v4f* __restrict__ xs4) {
    __shared__ uint32_t cur[NBUCKET + NBUCKET / 32];   // 33 KB padded
    __shared__ uint32_t ss[256];
    int t = threadIdx.x, blk = blockIdx.x;
    for (int j = t; j < NBUCKET; j += 256)
        cur[PADIDX(j)] = T[j];                   // coalesced T load
    __syncthreads();
    // serial exclusive scan of this thread's 32-run (padding -> conflict-free)
    uint32_t run = 0;
    int rb = t * 32;
    #pragma unroll
    for (int j = 0; j < 32; ++j) {
        uint32_t v = cur[PADIDX(rb + j)];
        cur[PADIDX(rb + j)] = run;
        run += v;
    }
    ss[t] = run;
    __syncthreads();
    #pragma unroll
    for (int off = 1; off < 256; off <<= 1) {
        uint32_t v = (t >= off) ? ss[t - off] : 0;
        __syncthreads();
        ss[t] += v;
        __syncthreads();
    }
    // add thread-range offset + this block's M row (coalesced)
    const uint32_t* __restrict__ Mrow = M + (size_t)blk * NBUCKET;
    for (int j = t; j < NBUCKET; j += 256) {
        uint32_t a = (j >> 5) ? ss[(j >> 5) - 1] : 0;
        cur[PADIDX(j)] += a + Mrow[j];
    }
    __syncthreads();
    for (int it = 0; it < PPB / 256; ++it) {
        int p = blk * PPB + it * 256 + t;
        float a = x[3*p], b = x[3*p+1], c = x[3*p+2];
        uint32_t k = morton13(a, b, c);
        uint32_t pos = atomicAdd(&cur[PADIDX(k)], 1u);   // LDS atomic -> global pos
        v4f v = {a, b, c, __uint_as_float((uint32_t)p)};
        xs4[pos] = v;
    }
}

// ---- pass 1 (phased, sorted input): blockIdx level-major -> device sweeps
// one level at a time (table XCD-L2-resident). ws chunk-blocked [c][level][t].
__global__ __launch_bounds__(256) void hash_enc_phase(const v4f* __restrict__ xs4,
                                                      const float* __restrict__ tables,
                                                      v2* __restrict__ ws) {
    int level = c_perm[blockIdx.x >> 12];           // 4096 chunks per level
    int c = blockIdx.x & 4095;
    int p = (c << 8) | threadIdx.x;
    v4f q = xs4[p];
    v2 r = enc_point_level(q.x, q.y, q.z, tables, level, c_res[level]);
    __builtin_nontemporal_store(r, ws + ((size_t)c << 12) + (level << 8) + threadIdx.x);
}

// ---- pass 2: cooperative-row stores (round-8 verified): assemble rows in
// registers, swizzled LDS redistribute, 8-lane groups store 128B rows as
// 2 FULL 64B lines -> scattered-store requests 8->2 per point.
__global__ __launch_bounds__(256) void untranspose7(const v2* __restrict__ ws,
                                                    const v4f* __restrict__ xs4,
                                                    v4f* __restrict__ out) {
    __shared__ v4f rows[256][8];                 // 32 KB
    __shared__ uint32_t ori[256];
    int t = threadIdx.x, c = blockIdx.x;
    const v2* __restrict__ base = ws + ((size_t)c << 12);
    v2 r[16];
    #pragma unroll
    for (int l = 0; l < 16; ++l)
        r[l] = base[(l << 8) | t];
    ori[t] = __float_as_uint(xs4[(c << 8) | t].w);
    #pragma unroll
    for (int q = 0; q < 8; ++q) {
        v4f v = {r[2*q].x, r[2*q].y, r[2*q+1].x, r[2*q+1].y};
        rows[t][(q + t) & 7] = v;                // swizzled: conflict-floor writes
    }
    __syncthreads();
    #pragma unroll
    for (int k = 0; k < 8; ++k) {
        int rr = (k << 5) | (t >> 3);            // row handled by this 8-lane group
        int q  = t & 7;                          // chunk within row
        v4f v = rows[rr][(q + rr) & 7];
        uint32_t o = ori[rr];
        out[(size_t)o * 8 + q] = v;
    }
}

// ---- fallback A (128MB ws only): unsorted phased pair (548us-class)
__global__ __launch_bounds__(256) void hash_enc_phase_u(const float* __restrict__ x,
                                                        const float* __restrict__ tables,
                                                        v2* __restrict__ ws) {
    int level = c_perm[blockIdx.x >> 12];
    int c = blockIdx.x & 4095;
    int p = (c << 8) | threadIdx.x;
    v2 r = enc_point_level(x[3*p], x[3*p+1], x[3*p+2], tables, level, c_res[level]);
    __builtin_nontemporal_store(r, ws + ((size_t)c << 12) + (level << 8) + threadIdx.x);
}
__global__ __launch_bounds__(256) void untranspose4(const v2* __restrict__ ws,
                                                    v4f* __restrict__ out) {
    __shared__ v4f tile[256][9];
    int t = threadIdx.x, c = blockIdx.x;
    const v2* __restrict__ base = ws + ((size_t)c << 12);
    v2 r[16];
    #pragma unroll
    for (int l = 0; l < 16; ++l)
        r[l] = base[(l << 8) | t];
    int keyw = (t >> 3) & 7;
    #pragma unroll
    for (int cc = 0; cc < 8; ++cc) {
        v4f v = {r[2*cc].x, r[2*cc].y, r[2*cc+1].x, r[2*cc+1].y};
        tile[t][(cc + keyw) & 7] = v;
    }
    __syncthreads();
    #pragma unroll
    for (int k = 0; k < 8; ++k) {
        int j  = (k << 8) | t;
        int pl = j >> 3, cc = j & 7;
        int key = (pl >> 3) & 7;
        v4f v = tile[pl][(cc + key) & 7];
        __builtin_nontemporal_store(v, out + ((size_t)c << 11) + j);
    }
}

// ---- fallback B (zero workspace): fused, correct, slow.
__global__ __launch_bounds__(256) void hash_enc_fused(const float* __restrict__ x,
                                                      const float* __restrict__ tables,
                                                      v2* __restrict__ out) {
    int tid = blockIdx.x * 256 + threadIdx.x;
    int level = tid & 15;
    int p = tid >> 4;
    v2 r = enc_point_level(x[3*p], x[3*p+1], x[3*p+2], tables, level, c_res[level]);
    out[tid] = r;
}

extern "C" void kernel_launch(void* const* d_in, const int* in_sizes, int n_in,
                              void* d_out, int out_size, void* d_ws, size_t ws_size,
                              hipStream_t stream) {
    const float* x      = (const float*)d_in[0];
    const float* tables = (const float*)d_in[1];
    const size_t WS_BYTES = (size_t)N_LEVELS * N_POINTS * sizeof(v2);    // 128 MB
    const size_t XS_BYTES = (size_t)N_POINTS * sizeof(v4f);              // 16 MB
    const size_t M_BYTES  = (size_t)HBLK * NBUCKET * sizeof(uint32_t);   // 8 MB
    const size_t T_BYTES  = (size_t)NBUCKET * sizeof(uint32_t);          // 32 KB
    size_t need_sort = WS_BYTES + XS_BYTES + M_BYTES + T_BYTES;

    if (ws_size >= need_sort) {
        char* wsb = (char*)d_ws;
        v2*       ws  = (v2*)wsb;
        v4f*      xs4 = (v4f*)(wsb + WS_BYTES);
        uint32_t* M   = (uint32_t*)(wsb + WS_BYTES + XS_BYTES);
        uint32_t* T   = (uint32_t*)(wsb + WS_BYTES + XS_BYTES + M_BYTES);
        k_hist   <<<dim3(HBLK),    dim3(256), 0, stream>>>(x, M);
        k_scanA  <<<dim3(NBUCKET), dim3(256), 0, stream>>>(M, T);
        k_scatter<<<dim3(HBLK),    dim3(256), 0, stream>>>(x, M, T, xs4);
        hash_enc_phase<<<dim3(65536), dim3(256), 0, stream>>>(xs4, tables, ws);
        untranspose7<<<dim3(4096), dim3(256), 0, stream>>>(ws, xs4, (v4f*)d_out);
    } else if (ws_size >= WS_BYTES) {
        hash_enc_phase_u<<<dim3(65536), dim3(256), 0, stream>>>(x, tables, (v2*)d_ws);
        untranspose4<<<dim3(4096), dim3(256), 0, stream>>>((const v2*)d_ws, (v4f*)d_out);
    } else {
        hash_enc_fused<<<dim3(65536), dim3(256), 0, stream>>>(x, tables, (v2*)d_out);
    }
}

// Round 10
// 454.345 us; speedup vs baseline: 1.1056x; 1.1056x over previous
//
#include <hip/hip_runtime.h>
#include <stdint.h>

#define N_POINTS   1048576
#define N_LEVELS   16
#define HASHMAP    524288u        // 1<<19
#define HASH_MASK  (HASHMAP - 1u)
#define PI1        2654435761u
#define PI2        805459861u
#define NBUCKET    4096           // 12-bit Morton key (res-16 cell)
#define HBLK       256            // hist/scatter blocks
#define PPB        4096           // points per hist/scatter block
#define RMAX       1024           // refine skips (never-occurring) huge buckets

typedef float v2  __attribute__((ext_vector_type(2)));   // one table entry (8B)
typedef float v4f __attribute__((ext_vector_type(4)));   // 16B chunk

// int(16 * (32^(1/15))^i) for i in 0..15, replicated exactly from the reference
__constant__ float c_res[16] = {16.f,20.f,25.f,32.f,40.f,50.f,64.f,80.f,
                                101.f,128.f,161.f,203.f,256.f,322.f,406.f,512.f};
// phase order: alternate coarse/fine so adjacent-in-time levels' tables fit L2
__constant__ int c_perm[16] = {0,15,1,14,2,13,3,12,4,11,5,10,6,9,7,8};

// ---- gather core (round-0 verified; L2-request-bound with sorted input)
__device__ __forceinline__ v2 enc_point_level(float x0, float x1, float x2,
                                              const float* __restrict__ tables,
                                              int level, float res) {
    float sx = x0*res, sy = x1*res, sz = x2*res;
    int ix = (int)sx, iy = (int)sy, iz = (int)sz;   // trunc == floor for x>=0
    float fx = sx - (float)ix, fy = sy - (float)iy, fz = sz - (float)iz;
    uint32_t hx0 = (uint32_t)ix,       hx1 = hx0 + 1u;
    uint32_t hy0 = (uint32_t)iy * PI1, hy1 = hy0 + PI1;
    uint32_t hz0 = (uint32_t)iz * PI2, hz1 = hz0 + PI2;
    const v2* __restrict__ tab = (const v2*)tables + (size_t)level * HASHMAP;
    uint32_t e0 = hy0 ^ hz0, e1 = hy1 ^ hz0, e2 = hy0 ^ hz1, e3 = hy1 ^ hz1;
    v2 f0 = tab[(hx0 ^ e0) & HASH_MASK], f1 = tab[(hx1 ^ e0) & HASH_MASK];
    v2 f2 = tab[(hx0 ^ e1) & HASH_MASK], f3 = tab[(hx1 ^ e1) & HASH_MASK];
    v2 f4 = tab[(hx0 ^ e2) & HASH_MASK], f5 = tab[(hx1 ^ e2) & HASH_MASK];
    v2 f6 = tab[(hx0 ^ e3) & HASH_MASK], f7 = tab[(hx1 ^ e3) & HASH_MASK];
    float wx1 = fx, wx0 = 1.f - fx;
    float wy1 = fy, wy0 = 1.f - fy;
    float wz1 = fz, wz0 = 1.f - fz;
    float w00 = wy0*wz0, w10 = wy1*wz0, w01 = wy0*wz1, w11 = wy1*wz1;
    float c0 = wx0*w00, c1 = wx1*w00, c2 = wx0*w10, c3 = wx1*w10;
    float c4 = wx0*w01, c5 = wx1*w01, c6 = wx0*w11, c7 = wx1*w11;
    v2 r;
    r.x = c0*f0.x + c1*f1.x + c2*f2.x + c3*f3.x + c4*f4.x + c5*f5.x + c6*f6.x + c7*f7.x;
    r.y = c0*f0.y + c1*f1.y + c2*f2.y + c3*f3.y + c4*f4.y + c5*f5.y + c6*f6.y + c7*f7.y;
    return r;
}

__device__ __forceinline__ uint32_t part1by2(uint32_t v) {
    v = (v | (v << 16)) & 0x030000FFu;
    v = (v | (v <<  8)) & 0x0300F00Fu;
    v = (v | (v <<  4)) & 0x030C30C3u;
    v = (v | (v <<  2)) & 0x09249249u;
    return v;
}
// 12-bit Morton of the res-16 cell (round-8 proven: cheapest sort machinery)
__device__ __forceinline__ uint32_t morton12(float x0, float x1, float x2) {
    uint32_t ix = (uint32_t)(int)(x0 * 16.f);   // x in [0,1) -> 0..15
    uint32_t iy = (uint32_t)(int)(x1 * 16.f);
    uint32_t iz = (uint32_t)(int)(x2 * 16.f);
    return part1by2(ix) | (part1by2(iy) << 1) | (part1by2(iz) << 2);
}
// 6-bit local Morton of the res-64 subcell within the res-16 bucket.
// x*64 == 4*(x*16) exactly (binary scaling) -> subcell bits consistent with
// the bucket key; [bucket12][local6] == exact 18-bit res-64 Morton order.
__device__ __forceinline__ uint32_t sub6(float x0, float x1, float x2) {
    uint32_t ix = (uint32_t)(int)(x0 * 64.f);
    uint32_t iy = (uint32_t)(int)(x1 * 64.f);
    uint32_t iz = (uint32_t)(int)(x2 * 64.f);
    return (ix & 1u) | ((iy & 1u) << 1) | ((iz & 1u) << 2)
         | ((ix & 2u) << 2) | ((iy & 2u) << 3) | ((iz & 2u) << 4);
}

// ---- 0a: per-block LDS histogram -> coalesced row write. Zero global atomics.
__global__ __launch_bounds__(256) void k_hist(const float* __restrict__ x,
                                              uint32_t* __restrict__ M) {
    __shared__ uint32_t h[NBUCKET];              // 16 KB
    int t = threadIdx.x, blk = blockIdx.x;
    for (int j = t; j < NBUCKET; j += 256) h[j] = 0;
    __syncthreads();
    int base = blk * PPB;
    for (int it = 0; it < PPB / 256; ++it) {
        int p = base + it * 256 + t;
        uint32_t k = morton12(x[3*p], x[3*p+1], x[3*p+2]);
        atomicAdd(&h[k], 1u);                    // LDS atomic
    }
    __syncthreads();
    for (int j = t; j < NBUCKET; j += 256)
        M[(size_t)blk * NBUCKET + j] = h[j];
}

// ---- 0b: per-bucket exclusive scan across the 256 hist-blocks (+ totals T).
__global__ __launch_bounds__(256) void k_scanA(uint32_t* __restrict__ M,
                                               uint32_t* __restrict__ T) {
    __shared__ uint32_t s[256];
    int t = threadIdx.x, b = blockIdx.x;
    uint32_t v0 = M[(size_t)t * NBUCKET + b];
    s[t] = v0;
    __syncthreads();
    #pragma unroll
    for (int off = 1; off < 256; off <<= 1) {
        uint32_t v = (t >= off) ? s[t - off] : 0;
        __syncthreads();
        s[t] += v;
        __syncthreads();
    }
    M[(size_t)t * NBUCKET + b] = s[t] - v0;      // excl. prefix over hist-blocks
    if (t == 255) T[b] = s[t];                   // bucket total
}

// ---- 0b2: exclusive scan of T -> Tstart[0..NBUCKET] (segment bounds for refine)
__global__ __launch_bounds__(256) void k_scanT(const uint32_t* __restrict__ T,
                                               uint32_t* __restrict__ Tstart) {
    __shared__ uint32_t ss[256];
    int t = threadIdx.x;
    uint32_t loc[NBUCKET / 256], sum = 0;
    #pragma unroll
    for (int j = 0; j < NBUCKET / 256; ++j) { loc[j] = T[t * (NBUCKET/256) + j]; sum += loc[j]; }
    ss[t] = sum;
    __syncthreads();
    #pragma unroll
    for (int off = 1; off < 256; off <<= 1) {
        uint32_t v = (t >= off) ? ss[t - off] : 0;
        __syncthreads();
        ss[t] += v;
        __syncthreads();
    }
    uint32_t run = ss[t] - sum;
    #pragma unroll
    for (int j = 0; j < NBUCKET / 256; ++j) { Tstart[t * (NBUCKET/256) + j] = run; run += loc[j]; }
    if (t == 255) Tstart[NBUCKET] = run;
}

// ---- 0c: scatter (round-8 proven form). Bucket bases from redundant LDS scan
// of T; ranks from LDS cursors. Zero global atomics; one coalesced read + one
// 16B scattered store per point. xs4 = (x,y,z,bitcast(orig)).
__global__ __launch_bounds__(256) void k_scatter(const float* __restrict__ x,
                                                 const uint32_t* __restrict__ M,
                                                 const uint32_t* __restrict__ T,
                                                 v4f* __restrict__ xs4) {
    __shared__ uint32_t sbase[NBUCKET];          // 16 KB
    __shared__ uint32_t cur[NBUCKET];            // 16 KB
    __shared__ uint32_t mrow[NBUCKET];           // 16 KB
    __shared__ uint32_t ss[256];
    int t = threadIdx.x, blk = blockIdx.x;
    uint32_t loc[16]; uint32_t sum = 0;
    #pragma unroll
    for (int j = 0; j < 16; ++j) { loc[j] = T[t * 16 + j]; sum += loc[j]; }
    ss[t] = sum;
    for (int j = t; j < NBUCKET; j += 256) {
        cur[j] = 0;
        mrow[j] = M[(size_t)blk * NBUCKET + j];
    }
    __syncthreads();
    #pragma unroll
    for (int off = 1; off < 256; off <<= 1) {
        uint32_t v = (t >= off) ? ss[t - off] : 0;
        __syncthreads();
        ss[t] += v;
        __syncthreads();
    }
    uint32_t run = ss[t] - sum;                  // exclusive prefix of thread range
    #pragma unroll
    for (int j = 0; j < 16; ++j) { sbase[t * 16 + j] = run; run += loc[j]; }
    __syncthreads();
    for (int it = 0; it < PPB / 256; ++it) {
        int p = blk * PPB + it * 256 + t;
        float a = x[3*p], b = x[3*p+1], c = x[3*p+2];
        uint32_t k = morton12(a, b, c);
        uint32_t rank = atomicAdd(&cur[k], 1u);  // LDS atomic
        uint32_t pos = sbase[k] + mrow[k] + rank;
        v4f v = {a, b, c, __uint_as_float((uint32_t)p)};
        xs4[pos] = v;
    }
}

// ---- 0d: per-bucket refine to exact res-64 Morton order. Block b counting-
// sorts bucket b's segment by the 6-bit local subkey, in place via LDS
// buffering. Pure ordering optimization: skipping (n>RMAX, never for uniform
// input) or any permutation is still CORRECT — orig rides inside xs4.w.
__global__ __launch_bounds__(256) void k_refine(v4f* __restrict__ xs4,
                                                const uint32_t* __restrict__ Tstart) {
    __shared__ v4f buf[RMAX];                    // 16 KB
    __shared__ uint32_t h[64];
    __shared__ uint32_t cur[64];
    int b = blockIdx.x, t = threadIdx.x;
    uint32_t s = Tstart[b], e = Tstart[b + 1];
    int n = (int)(e - s);
    if (n > RMAX) return;                        // ordering-only: safe to skip
    if (t < 64) h[t] = 0;
    for (int i = t; i < n; i += 256) buf[i] = xs4[s + i];
    __syncthreads();
    for (int i = t; i < n; i += 256) {
        v4f q = buf[i];
        atomicAdd(&h[sub6(q.x, q.y, q.z)], 1u);
    }
    __syncthreads();
    if (t == 0) {                                // tiny serial scan of 64
        uint32_t run = 0;
        #pragma unroll
        for (int j = 0; j < 64; ++j) { cur[j] = run; run += h[j]; }
    }
    __syncthreads();
    for (int i = t; i < n; i += 256) {
        v4f q = buf[i];
        uint32_t pos = atomicAdd(&cur[sub6(q.x, q.y, q.z)], 1u);
        xs4[s + pos] = q;
    }
}

// ---- pass 1 (phased, sorted input): blockIdx level-major -> device sweeps
// one level at a time (table XCD-L2-resident). ws chunk-blocked [c][level][t].
__global__ __launch_bounds__(256) void hash_enc_phase(const v4f* __restrict__ xs4,
                                                      const float* __restrict__ tables,
                                                      v2* __restrict__ ws) {
    int level = c_perm[blockIdx.x >> 12];           // 4096 chunks per level
    int c = blockIdx.x & 4095;
    int p = (c << 8) | threadIdx.x;
    v4f q = xs4[p];
    v2 r = enc_point_level(q.x, q.y, q.z, tables, level, c_res[level]);
    __builtin_nontemporal_store(r, ws + ((size_t)c << 12) + (level << 8) + threadIdx.x);
}

// ---- pass 2: cooperative-row stores (round-8 verified): assemble rows in
// registers, swizzled LDS redistribute, 8-lane groups store 128B rows as
// 2 FULL 64B lines -> scattered-store requests 8->2 per point.
__global__ __launch_bounds__(256) void untranspose7(const v2* __restrict__ ws,
                                                    const v4f* __restrict__ xs4,
                                                    v4f* __restrict__ out) {
    __shared__ v4f rows[256][8];                 // 32 KB
    __shared__ uint32_t ori[256];
    int t = threadIdx.x, c = blockIdx.x;
    const v2* __restrict__ base = ws + ((size_t)c << 12);
    v2 r[16];
    #pragma unroll
    for (int l = 0; l < 16; ++l)
        r[l] = base[(l << 8) | t];
    ori[t] = __float_as_uint(xs4[(c << 8) | t].w);
    #pragma unroll
    for (int q = 0; q < 8; ++q) {
        v4f v = {r[2*q].x, r[2*q].y, r[2*q+1].x, r[2*q+1].y};
        rows[t][(q + t) & 7] = v;                // swizzled: conflict-floor writes
    }
    __syncthreads();
    #pragma unroll
    for (int k = 0; k < 8; ++k) {
        int rr = (k << 5) | (t >> 3);            // row handled by this 8-lane group
        int q  = t & 7;                          // chunk within row
        v4f v = rows[rr][(q + rr) & 7];
        uint32_t o = ori[rr];
        out[(size_t)o * 8 + q] = v;
    }
}

// ---- fallback A (128MB ws only): unsorted phased pair (548us-class)
__global__ __launch_bounds__(256) void hash_enc_phase_u(const float* __restrict__ x,
                                                        const float* __restrict__ tables,
                                                        v2* __restrict__ ws) {
    int level = c_perm[blockIdx.x >> 12];
    int c = blockIdx.x & 4095;
    int p = (c << 8) | threadIdx.x;
    v2 r = enc_point_level(x[3*p], x[3*p+1], x[3*p+2], tables, level, c_res[level]);
    __builtin_nontemporal_store(r, ws + ((size_t)c << 12) + (level << 8) + threadIdx.x);
}
__global__ __launch_bounds__(256) void untranspose4(const v2* __restrict__ ws,
                                                    v4f* __restrict__ out) {
    __shared__ v4f tile[256][9];
    int t = threadIdx.x, c = blockIdx.x;
    const v2* __restrict__ base = ws + ((size_t)c << 12);
    v2 r[16];
    #pragma unroll
    for (int l = 0; l < 16; ++l)
        r[l] = base[(l << 8) | t];
    int keyw = (t >> 3) & 7;
    #pragma unroll
    for (int cc = 0; cc < 8; ++cc) {
        v4f v = {r[2*cc].x, r[2*cc].y, r[2*cc+1].x, r[2*cc+1].y};
        tile[t][(cc + keyw) & 7] = v;
    }
    __syncthreads();
    #pragma unroll
    for (int k = 0; k < 8; ++k) {
        int j  = (k << 8) | t;
        int pl = j >> 3, cc = j & 7;
        int key = (pl >> 3) & 7;
        v4f v = tile[pl][(cc + key) & 7];
        __builtin_nontemporal_store(v, out + ((size_t)c << 11) + j);
    }
}

// ---- fallback B (zero workspace): fused, correct, slow.
__global__ __launch_bounds__(256) void hash_enc_fused(const float* __restrict__ x,
                                                      const float* __restrict__ tables,
                                                      v2* __restrict__ out) {
    int tid = blockIdx.x * 256 + threadIdx.x;
    int level = tid & 15;
    int p = tid >> 4;
    v2 r = enc_point_level(x[3*p], x[3*p+1], x[3*p+2], tables, level, c_res[level]);
    out[tid] = r;
}

extern "C" void kernel_launch(void* const* d_in, const int* in_sizes, int n_in,
                              void* d_out, int out_size, void* d_ws, size_t ws_size,
                              hipStream_t stream) {
    const float* x      = (const float*)d_in[0];
    const float* tables = (const float*)d_in[1];
    const size_t WS_BYTES = (size_t)N_LEVELS * N_POINTS * sizeof(v2);    // 128 MB
    const size_t XS_BYTES = (size_t)N_POINTS * sizeof(v4f);              // 16 MB
    const size_t M_BYTES  = (size_t)HBLK * NBUCKET * sizeof(uint32_t);   // 4 MB
    const size_t T_BYTES  = (size_t)NBUCKET * sizeof(uint32_t);          // 16 KB
    const size_t TS_BYTES = (size_t)(NBUCKET + 1) * sizeof(uint32_t);    // 16 KB
    size_t need_sort = WS_BYTES + XS_BYTES + M_BYTES + T_BYTES + TS_BYTES;

    if (ws_size >= need_sort) {
        char* wsb = (char*)d_ws;
        v2*       ws  = (v2*)wsb;
        v4f*      xs4 = (v4f*)(wsb + WS_BYTES);
        uint32_t* M   = (uint32_t*)(wsb + WS_BYTES + XS_BYTES);
        uint32_t* T   = (uint32_t*)(wsb + WS_BYTES + XS_BYTES + M_BYTES);
        uint32_t* Ts  = (uint32_t*)(wsb + WS_BYTES + XS_BYTES + M_BYTES + T_BYTES);
        k_hist   <<<dim3(HBLK),    dim3(256), 0, stream>>>(x, M);
        k_scanA  <<<dim3(NBUCKET), dim3(256), 0, stream>>>(M, T);
        k_scanT  <<<dim3(1),       dim3(256), 0, stream>>>(T, Ts);
        k_scatter<<<dim3(HBLK),    dim3(256), 0, stream>>>(x, M, T, xs4);
        k_refine <<<dim3(NBUCKET), dim3(256), 0, stream>>>(xs4, Ts);
        hash_enc_phase<<<dim3(65536), dim3(256), 0, stream>>>(xs4, tables, ws);
        untranspose7<<<dim3(4096), dim3(256), 0, stream>>>(ws, xs4, (v4f*)d_out);
    } else if (ws_size >= WS_BYTES) {
        hash_enc_phase_u<<<dim3(65536), dim3(256), 0, stream>>>(x, tables, (v2*)d_ws);
        untranspose4<<<dim3(4096), dim3(256), 0, stream>>>((const v2*)d_ws, (v4f*)d_out);
    } else {
        hash_enc_fused<<<dim3(65536), dim3(256), 0, stream>>>(x, tables, (v2*)d_out);
    }
}

// Round 11
// 450.635 us; speedup vs baseline: 1.1147x; 1.0082x over previous
//
#include <hip/hip_runtime.h>
#include <stdint.h>

#define N_POINTS   1048576
#define N_LEVELS   16
#define HASHMAP    524288u        // 1<<19
#define HASH_MASK  (HASHMAP - 1u)
#define PI1        2654435761u
#define PI2        805459861u
#define NBUCKET    4096           // 12-bit Morton key (res-16 cell)
#define HBLK       256            // hist/scatter blocks
#define PPB        4096           // points per hist/scatter block
#define RMAX       1024           // refine skips (never-occurring) huge buckets

typedef float v2  __attribute__((ext_vector_type(2)));   // one table entry (8B)
typedef float v4f __attribute__((ext_vector_type(4)));   // 16B chunk

// int(16 * (32^(1/15))^i) for i in 0..15, replicated exactly from the reference
__constant__ float c_res[16] = {16.f,20.f,25.f,32.f,40.f,50.f,64.f,80.f,
                                101.f,128.f,161.f,203.f,256.f,322.f,406.f,512.f};
// phase order: alternate coarse/fine so adjacent-in-time levels' tables fit L2
__constant__ int c_perm[16] = {0,15,1,14,2,13,3,12,4,11,5,10,6,9,7,8};

// ---- gather core (round-0 verified; at the L2-request floor with sorted input:
// fine levels are sparser than point density -> ~6 distinct lines/pt,
// irreducible; 60M total requests / 307 G/s ~= 190us == measured)
__device__ __forceinline__ v2 enc_point_level(float x0, float x1, float x2,
                                              const float* __restrict__ tables,
                                              int level, float res) {
    float sx = x0*res, sy = x1*res, sz = x2*res;
    int ix = (int)sx, iy = (int)sy, iz = (int)sz;   // trunc == floor for x>=0
    float fx = sx - (float)ix, fy = sy - (float)iy, fz = sz - (float)iz;
    uint32_t hx0 = (uint32_t)ix,       hx1 = hx0 + 1u;
    uint32_t hy0 = (uint32_t)iy * PI1, hy1 = hy0 + PI1;
    uint32_t hz0 = (uint32_t)iz * PI2, hz1 = hz0 + PI2;
    const v2* __restrict__ tab = (const v2*)tables + (size_t)level * HASHMAP;
    uint32_t e0 = hy0 ^ hz0, e1 = hy1 ^ hz0, e2 = hy0 ^ hz1, e3 = hy1 ^ hz1;
    v2 f0 = tab[(hx0 ^ e0) & HASH_MASK], f1 = tab[(hx1 ^ e0) & HASH_MASK];
    v2 f2 = tab[(hx0 ^ e1) & HASH_MASK], f3 = tab[(hx1 ^ e1) & HASH_MASK];
    v2 f4 = tab[(hx0 ^ e2) & HASH_MASK], f5 = tab[(hx1 ^ e2) & HASH_MASK];
    v2 f6 = tab[(hx0 ^ e3) & HASH_MASK], f7 = tab[(hx1 ^ e3) & HASH_MASK];
    float wx1 = fx, wx0 = 1.f - fx;
    float wy1 = fy, wy0 = 1.f - fy;
    float wz1 = fz, wz0 = 1.f - fz;
    float w00 = wy0*wz0, w10 = wy1*wz0, w01 = wy0*wz1, w11 = wy1*wz1;
    float c0 = wx0*w00, c1 = wx1*w00, c2 = wx0*w10, c3 = wx1*w10;
    float c4 = wx0*w01, c5 = wx1*w01, c6 = wx0*w11, c7 = wx1*w11;
    v2 r;
    r.x = c0*f0.x + c1*f1.x + c2*f2.x + c3*f3.x + c4*f4.x + c5*f5.x + c6*f6.x + c7*f7.x;
    r.y = c0*f0.y + c1*f1.y + c2*f2.y + c3*f3.y + c4*f4.y + c5*f5.y + c6*f6.y + c7*f7.y;
    return r;
}

__device__ __forceinline__ uint32_t part1by2(uint32_t v) {
    v = (v | (v << 16)) & 0x030000FFu;
    v = (v | (v <<  8)) & 0x0300F00Fu;
    v = (v | (v <<  4)) & 0x030C30C3u;
    v = (v | (v <<  2)) & 0x09249249u;
    return v;
}
// 12-bit Morton of the res-16 cell (round-8 proven: cheapest sort machinery)
__device__ __forceinline__ uint32_t morton12(float x0, float x1, float x2) {
    uint32_t ix = (uint32_t)(int)(x0 * 16.f);   // x in [0,1) -> 0..15
    uint32_t iy = (uint32_t)(int)(x1 * 16.f);
    uint32_t iz = (uint32_t)(int)(x2 * 16.f);
    return part1by2(ix) | (part1by2(iy) << 1) | (part1by2(iz) << 2);
}
// 9-bit local Morton of the res-128 subcell within the res-16 bucket.
// x*128 == 8*(x*16) exactly (binary scaling) -> subcell bits consistent with
// the bucket key; [bucket12][local9] == exact 21-bit res-128 Morton order.
__device__ __forceinline__ uint32_t sub9(float x0, float x1, float x2) {
    uint32_t ix = (uint32_t)(int)(x0 * 128.f);
    uint32_t iy = (uint32_t)(int)(x1 * 128.f);
    uint32_t iz = (uint32_t)(int)(x2 * 128.f);
    return  (ix & 1u)        | ((iy & 1u) << 1) | ((iz & 1u) << 2)
         | ((ix & 2u) << 2)  | ((iy & 2u) << 3) | ((iz & 2u) << 4)
         | ((ix & 4u) << 4)  | ((iy & 4u) << 5) | ((iz & 4u) << 6);
}

// ---- 0a: per-block LDS histogram -> coalesced row write. Zero global atomics.
__global__ __launch_bounds__(256) void k_hist(const float* __restrict__ x,
                                              uint32_t* __restrict__ M) {
    __shared__ uint32_t h[NBUCKET];              // 16 KB
    int t = threadIdx.x, blk = blockIdx.x;
    for (int j = t; j < NBUCKET; j += 256) h[j] = 0;
    __syncthreads();
    int base = blk * PPB;
    for (int it = 0; it < PPB / 256; ++it) {
        int p = base + it * 256 + t;
        uint32_t k = morton12(x[3*p], x[3*p+1], x[3*p+2]);
        atomicAdd(&h[k], 1u);                    // LDS atomic
    }
    __syncthreads();
    for (int j = t; j < NBUCKET; j += 256)
        M[(size_t)blk * NBUCKET + j] = h[j];
}

// ---- 0b: per-bucket exclusive scan across the 256 hist-blocks (+ totals T).
__global__ __launch_bounds__(256) void k_scanA(uint32_t* __restrict__ M,
                                               uint32_t* __restrict__ T) {
    __shared__ uint32_t s[256];
    int t = threadIdx.x, b = blockIdx.x;
    uint32_t v0 = M[(size_t)t * NBUCKET + b];
    s[t] = v0;
    __syncthreads();
    #pragma unroll
    for (int off = 1; off < 256; off <<= 1) {
        uint32_t v = (t >= off) ? s[t - off] : 0;
        __syncthreads();
        s[t] += v;
        __syncthreads();
    }
    M[(size_t)t * NBUCKET + b] = s[t] - v0;      // excl. prefix over hist-blocks
    if (t == 255) T[b] = s[t];                   // bucket total
}

// ---- 0c: scatter (round-8 proven form). Bucket bases from redundant LDS scan
// of T; ranks from LDS cursors. Zero global atomics; one coalesced read + one
// 16B scattered store per point. xs4 = (x,y,z,bitcast(orig)).
// Block 0 also publishes the bucket starts (sbase == Tstart) for k_refine —
// this replaces round-10's separate k_scanT dispatch.
__global__ __launch_bounds__(256) void k_scatter(const float* __restrict__ x,
                                                 const uint32_t* __restrict__ M,
                                                 const uint32_t* __restrict__ T,
                                                 v4f* __restrict__ xs4,
                                                 uint32_t* __restrict__ Tstart) {
    __shared__ uint32_t sbase[NBUCKET];          // 16 KB
    __shared__ uint32_t cur[NBUCKET];            // 16 KB
    __shared__ uint32_t mrow[NBUCKET];           // 16 KB
    __shared__ uint32_t ss[256];
    int t = threadIdx.x, blk = blockIdx.x;
    uint32_t loc[16]; uint32_t sum = 0;
    #pragma unroll
    for (int j = 0; j < 16; ++j) { loc[j] = T[t * 16 + j]; sum += loc[j]; }
    ss[t] = sum;
    for (int j = t; j < NBUCKET; j += 256) {
        cur[j] = 0;
        mrow[j] = M[(size_t)blk * NBUCKET + j];
    }
    __syncthreads();
    #pragma unroll
    for (int off = 1; off < 256; off <<= 1) {
        uint32_t v = (t >= off) ? ss[t - off] : 0;
        __syncthreads();
        ss[t] += v;
        __syncthreads();
    }
    uint32_t run = ss[t] - sum;                  // exclusive prefix of thread range
    #pragma unroll
    for (int j = 0; j < 16; ++j) { sbase[t * 16 + j] = run; run += loc[j]; }
    __syncthreads();
    if (blk == 0) {                              // publish Tstart (no extra dispatch)
        for (int j = t; j < NBUCKET; j += 256) Tstart[j] = sbase[j];
        if (t == 0) Tstart[NBUCKET] = (uint32_t)N_POINTS;
    }
    for (int it = 0; it < PPB / 256; ++it) {
        int p = blk * PPB + it * 256 + t;
        float a = x[3*p], b = x[3*p+1], c = x[3*p+2];
        uint32_t k = morton12(a, b, c);
        uint32_t rank = atomicAdd(&cur[k], 1u);  // LDS atomic
        uint32_t pos = sbase[k] + mrow[k] + rank;
        v4f v = {a, b, c, __uint_as_float((uint32_t)p)};
        xs4[pos] = v;
    }
}

// ---- 0d: per-bucket refine to exact res-128 Morton order (9-bit subkey).
// Block b counting-sorts bucket b's segment in place via LDS buffering.
// Pure ordering optimization: skipping (n>RMAX, never for uniform input) or
// any permutation is still CORRECT — orig rides inside xs4.w.
__global__ __launch_bounds__(256) void k_refine(v4f* __restrict__ xs4,
                                                const uint32_t* __restrict__ Tstart) {
    __shared__ v4f buf[RMAX];                    // 16 KB
    __shared__ uint32_t h[512];
    __shared__ uint32_t cur[512];
    __shared__ uint32_t ss[256];
    int b = blockIdx.x, t = threadIdx.x;
    uint32_t s = Tstart[b], e = Tstart[b + 1];
    int n = (int)(e - s);
    if (n > RMAX) return;                        // ordering-only: safe to skip
    h[t] = 0; h[t + 256] = 0;
    for (int i = t; i < n; i += 256) buf[i] = xs4[s + i];
    __syncthreads();
    for (int i = t; i < n; i += 256) {
        v4f q = buf[i];
        atomicAdd(&h[sub9(q.x, q.y, q.z)], 1u);
    }
    __syncthreads();
    uint32_t a0 = h[2*t], a1 = h[2*t + 1];       // parallel scan over 512
    ss[t] = a0 + a1;
    __syncthreads();
    #pragma unroll
    for (int off = 1; off < 256; off <<= 1) {
        uint32_t v = (t >= off) ? ss[t - off] : 0;
        __syncthreads();
        ss[t] += v;
        __syncthreads();
    }
    uint32_t pre = t ? ss[t - 1] : 0;
    cur[2*t] = pre; cur[2*t + 1] = pre + a0;
    __syncthreads();
    for (int i = t; i < n; i += 256) {
        v4f q = buf[i];
        uint32_t pos = atomicAdd(&cur[sub9(q.x, q.y, q.z)], 1u);
        xs4[s + pos] = q;
    }
}

// ---- pass 1 (phased, sorted input): blockIdx level-major -> device sweeps
// one level at a time (table XCD-L2-resident). ws chunk-blocked [c][level][t].
__global__ __launch_bounds__(256) void hash_enc_phase(const v4f* __restrict__ xs4,
                                                      const float* __restrict__ tables,
                                                      v2* __restrict__ ws) {
    int level = c_perm[blockIdx.x >> 12];           // 4096 chunks per level
    int c = blockIdx.x & 4095;
    int p = (c << 8) | threadIdx.x;
    v4f q = xs4[p];
    v2 r = enc_point_level(q.x, q.y, q.z, tables, level, c_res[level]);
    __builtin_nontemporal_store(r, ws + ((size_t)c << 12) + (level << 8) + threadIdx.x);
}

// ---- pass 2: cooperative-row stores (round-8 verified): assemble rows in
// registers, swizzled LDS redistribute, 8-lane groups store 128B rows as
// 2 FULL 64B lines -> scattered-store requests 8->2 per point.
__global__ __launch_bounds__(256) void untranspose7(const v2* __restrict__ ws,
                                                    const v4f* __restrict__ xs4,
                                                    v4f* __restrict__ out) {
    __shared__ v4f rows[256][8];                 // 32 KB
    __shared__ uint32_t ori[256];
    int t = threadIdx.x, c = blockIdx.x;
    const v2* __restrict__ base = ws + ((size_t)c << 12);
    v2 r[16];
    #pragma unroll
    for (int l = 0; l < 16; ++l)
        r[l] = base[(l << 8) | t];
    ori[t] = __float_as_uint(xs4[(c << 8) | t].w);
    #pragma unroll
    for (int q = 0; q < 8; ++q) {
        v4f v = {r[2*q].x, r[2*q].y, r[2*q+1].x, r[2*q+1].y};
        rows[t][(q + t) & 7] = v;                // swizzled: conflict-floor writes
    }
    __syncthreads();
    #pragma unroll
    for (int k = 0; k < 8; ++k) {
        int rr = (k << 5) | (t >> 3);            // row handled by this 8-lane group
        int q  = t & 7;                          // chunk within row
        v4f v = rows[rr][(q + rr) & 7];
        uint32_t o = ori[rr];
        out[(size_t)o * 8 + q] = v;
    }
}

// ---- fallback A (128MB ws only): unsorted phased pair (548us-class)
__global__ __launch_bounds__(256) void hash_enc_phase_u(const float* __restrict__ x,
                                                        const float* __restrict__ tables,
                                                        v2* __restrict__ ws) {
    int level = c_perm[blockIdx.x >> 12];
    int c = blockIdx.x & 4095;
    int p = (c << 8) | threadIdx.x;
    v2 r = enc_point_level(x[3*p], x[3*p+1], x[3*p+2], tables, level, c_res[level]);
    __builtin_nontemporal_store(r, ws + ((size_t)c << 12) + (level << 8) + threadIdx.x);
}
__global__ __launch_bounds__(256) void untranspose4(const v2* __restrict__ ws,
                                                    v4f* __restrict__ out) {
    __shared__ v4f tile[256][9];
    int t = threadIdx.x, c = blockIdx.x;
    const v2* __restrict__ base = ws + ((size_t)c << 12);
    v2 r[16];
    #pragma unroll
    for (int l = 0; l < 16; ++l)
        r[l] = base[(l << 8) | t];
    int keyw = (t >> 3) & 7;
    #pragma unroll
    for (int cc = 0; cc < 8; ++cc) {
        v4f v = {r[2*cc].x, r[2*cc].y, r[2*cc+1].x, r[2*cc+1].y};
        tile[t][(cc + keyw) & 7] = v;
    }
    __syncthreads();
    #pragma unroll
    for (int k = 0; k < 8; ++k) {
        int j  = (k << 8) | t;
        int pl = j >> 3, cc = j & 7;
        int key = (pl >> 3) & 7;
        v4f v = tile[pl][(cc + key) & 7];
        __builtin_nontemporal_store(v, out + ((size_t)c << 11) + j);
    }
}

// ---- fallback B (zero workspace): fused, correct, slow.
__global__ __launch_bounds__(256) void hash_enc_fused(const float* __restrict__ x,
                                                      const float* __restrict__ tables,
                                                      v2* __restrict__ out) {
    int tid = blockIdx.x * 256 + threadIdx.x;
    int level = tid & 15;
    int p = tid >> 4;
    v2 r = enc_point_level(x[3*p], x[3*p+1], x[3*p+2], tables, level, c_res[level]);
    out[tid] = r;
}

extern "C" void kernel_launch(void* const* d_in, const int* in_sizes, int n_in,
                              void* d_out, int out_size, void* d_ws, size_t ws_size,
                              hipStream_t stream) {
    const float* x      = (const float*)d_in[0];
    const float* tables = (const float*)d_in[1];
    const size_t WS_BYTES = (size_t)N_LEVELS * N_POINTS * sizeof(v2);    // 128 MB
    const size_t XS_BYTES = (size_t)N_POINTS * sizeof(v4f);              // 16 MB
    const size_t M_BYTES  = (size_t)HBLK * NBUCKET * sizeof(uint32_t);   // 4 MB
    const size_t T_BYTES  = (size_t)NBUCKET * sizeof(uint32_t);          // 16 KB
    const size_t TS_BYTES = (size_t)(NBUCKET + 1) * sizeof(uint32_t);    // 16 KB
    size_t need_sort = WS_BYTES + XS_BYTES + M_BYTES + T_BYTES + TS_BYTES;

    if (ws_size >= need_sort) {
        char* wsb = (char*)d_ws;
        v2*       ws  = (v2*)wsb;
        v4f*      xs4 = (v4f*)(wsb + WS_BYTES);
        uint32_t* M   = (uint32_t*)(wsb + WS_BYTES + XS_BYTES);
        uint32_t* T   = (uint32_t*)(wsb + WS_BYTES + XS_BYTES + M_BYTES);
        uint32_t* Ts  = (uint32_t*)(wsb + WS_BYTES + XS_BYTES + M_BYTES + T_BYTES);
        k_hist   <<<dim3(HBLK),    dim3(256), 0, stream>>>(x, M);
        k_scanA  <<<dim3(NBUCKET), dim3(256), 0, stream>>>(M, T);
        k_scatter<<<dim3(HBLK),    dim3(256), 0, stream>>>(x, M, T, xs4, Ts);
        k_refine <<<dim3(NBUCKET), dim3(256), 0, stream>>>(xs4, Ts);
        hash_enc_phase<<<dim3(65536), dim3(256), 0, stream>>>(xs4, tables, ws);
        untranspose7<<<dim3(4096), dim3(256), 0, stream>>>(ws, xs4, (v4f*)d_out);
    } else if (ws_size >= WS_BYTES) {
        hash_enc_phase_u<<<dim3(65536), dim3(256), 0, stream>>>(x, tables, (v2*)d_ws);
        untranspose4<<<dim3(4096), dim3(256), 0, stream>>>((const v2*)d_ws, (v4f*)d_out);
    } else {
        hash_enc_fused<<<dim3(65536), dim3(256), 0, stream>>>(x, tables, (v2*)d_out);
    }
}